// Round 3
// baseline (66.994 us; speedup 1.0000x reference)
//
#include <hip/hip_runtime.h>

// out(p) = (48 - (g(p)·G(p) - g(p)·g(p))) / 8
//   g = x / max(||x||_2 over C, 1e-8), G = 7x7 zero-padded box-sum of g.
// LDS holds packed-bf16 pairs; one buffer aliased: g-phase then h-phase.
// Center g recomputed from global (L2-hot) in stage 3.

typedef float f32x2 __attribute__((ext_vector_type(2)));
typedef float f32x4 __attribute__((ext_vector_type(4)));
typedef unsigned int u32;

#define EPS2 1e-16f   // max(sqrt(n2),1e-8)^-1 == rsq(max(n2,1e-16))

constexpr int TW  = 64;       // tile width  (out)
constexpr int TH  = 32;       // tile height (out)
constexpr int RIN = TH + 6;   // 38 staged rows
constexpr int GU  = 36;       // u32 per LDS row (72 bf16 cols; 144B, 16B-mult)
// g phase: LDS col c (bf16) = image col x0 + c - 4, c in [0,72)
// h phase: LDS col j (bf16) = out col j, u32 idx j/2 in [0,32)

__device__ __forceinline__ u32 packbf2(float a, float b) {
    // round-half-up to bf16, pack (a=lo, b=hi). Values bounded (|g|<=1, |h|<=7).
    const u32 ua = __float_as_uint(a), ub = __float_as_uint(b);
    return ((ua + 0x8000u) >> 16) | ((ub + 0x8000u) & 0xffff0000u);
}
__device__ __forceinline__ f32x2 up2(u32 u) {
    f32x2 r;
    r.x = __uint_as_float(u << 16);
    r.y = __uint_as_float(u & 0xffff0000u);
    return r;
}

__global__ __launch_bounds__(256, 6) void mcnd_kernel(const float* __restrict__ x,
                                                      float* __restrict__ out,
                                                      int B, int H, int W) {
    __shared__ __align__(16) u32 lds[3][RIN][GU];   // 16,416 B

    const int HW = H * W;
    const int tilesX = W / TW;                  // 8
    const int tilesPerImg = tilesX * (H / TH);  // 128

    const int b  = blockIdx.x / tilesPerImg;
    const int t  = blockIdx.x % tilesPerImg;
    const int ty = t / tilesX;
    const int tx = t % tilesX;
    const int y0 = ty * TH;
    const int x0 = tx * TW;

    const float* __restrict__ xb = x + (size_t)b * 3 * HW;
    const int tid = threadIdx.x;

    // ---- stage 1: load + normalize -> packed bf16 g in LDS ----
    for (int p = tid; p < RIN * 9; p += 256) {
        const int r  = p / 9;
        const int k  = p - r * 9;
        const int gy = y0 + r - 3;
        const int gx = x0 + 8 * k - 4;          // 16B-aligned f32 col base
        f32x4 va0 = {0.f,0.f,0.f,0.f}, va1 = va0;
        f32x4 vb0 = va0, vb1 = va0, vc0 = va0, vc1 = va0;
        if (gy >= 0 && gy < H) {
            const float* base = xb + (size_t)gy * W + gx;
            if (gx >= 0) {                      // left 4-col chunk wholly in/out
                va0 = *(const f32x4*)(base);
                vb0 = *(const f32x4*)(base + HW);
                vc0 = *(const f32x4*)(base + 2 * HW);
            }
            if (gx + 8 <= W) {                  // right 4-col chunk
                va1 = *(const f32x4*)(base + 4);
                vb1 = *(const f32x4*)(base + HW + 4);
                vc1 = *(const f32x4*)(base + 2 * HW + 4);
            }
        }
        float ga[8], gb[8], gc[8];
#pragma unroll
        for (int e = 0; e < 4; ++e) {
            {
                const float n2  = va0[e]*va0[e] + vb0[e]*vb0[e] + vc0[e]*vc0[e];
                const float inv = __builtin_amdgcn_rsqf(fmaxf(n2, EPS2));
                ga[e] = va0[e]*inv; gb[e] = vb0[e]*inv; gc[e] = vc0[e]*inv;
            }
            {
                const float n2  = va1[e]*va1[e] + vb1[e]*vb1[e] + vc1[e]*vc1[e];
                const float inv = __builtin_amdgcn_rsqf(fmaxf(n2, EPS2));
                ga[e+4] = va1[e]*inv; gb[e+4] = vb1[e]*inv; gc[e+4] = vc1[e]*inv;
            }
        }
        uint4 wa, wb, wc;
        wa.x = packbf2(ga[0],ga[1]); wa.y = packbf2(ga[2],ga[3]);
        wa.z = packbf2(ga[4],ga[5]); wa.w = packbf2(ga[6],ga[7]);
        wb.x = packbf2(gb[0],gb[1]); wb.y = packbf2(gb[2],gb[3]);
        wb.z = packbf2(gb[4],gb[5]); wb.w = packbf2(gb[6],gb[7]);
        wc.x = packbf2(gc[0],gc[1]); wc.y = packbf2(gc[2],gc[3]);
        wc.z = packbf2(gc[4],gc[5]); wc.w = packbf2(gc[6],gc[7]);
        *(uint4*)&lds[0][r][4*k] = wa;
        *(uint4*)&lds[1][r][4*k] = wb;
        *(uint4*)&lds[2][r][4*k] = wc;
    }
    __syncthreads();

    // ---- stage 2a: horizontal 7-tap into registers (16 out cols / thread) ----
    u32 hreg[3][8];
    const int r2 = tid >> 2, q = tid & 3;
    const bool act2 = tid < RIN * 4;            // 152 active
    if (act2) {
#pragma unroll
        for (int ch = 0; ch < 3; ++ch) {
            const u32* row = &lds[ch][r2][0];
            const uint4 U0 = *(const uint4*)(row + 8*q);
            const uint4 U1 = *(const uint4*)(row + 8*q + 4);
            const uint4 U2 = *(const uint4*)(row + 8*q + 8);
            float c[24];
            f32x2 d;
            d = up2(U0.x); c[0]=d.x;  c[1]=d.y;
            d = up2(U0.y); c[2]=d.x;  c[3]=d.y;
            d = up2(U0.z); c[4]=d.x;  c[5]=d.y;
            d = up2(U0.w); c[6]=d.x;  c[7]=d.y;
            d = up2(U1.x); c[8]=d.x;  c[9]=d.y;
            d = up2(U1.y); c[10]=d.x; c[11]=d.y;
            d = up2(U1.z); c[12]=d.x; c[13]=d.y;
            d = up2(U1.w); c[14]=d.x; c[15]=d.y;
            d = up2(U2.x); c[16]=d.x; c[17]=d.y;
            d = up2(U2.y); c[18]=d.x; c[19]=d.y;
            d = up2(U2.z); c[20]=d.x; c[21]=d.y;
            d = up2(U2.w); c[22]=d.x; c[23]=d.y;
            float hp[16];
            hp[0] = c[1]+c[2]+c[3]+c[4]+c[5]+c[6]+c[7];
#pragma unroll
            for (int m = 1; m < 16; ++m) hp[m] = hp[m-1] - c[m] + c[m+7];
#pragma unroll
            for (int m = 0; m < 8; ++m) hreg[ch][m] = packbf2(hp[2*m], hp[2*m+1]);
        }
    }
    __syncthreads();
    // ---- stage 2b: write h over g (aliased) ----
    if (act2) {
#pragma unroll
        for (int ch = 0; ch < 3; ++ch) {
            uint4 w0, w1;
            w0.x = hreg[ch][0]; w0.y = hreg[ch][1]; w0.z = hreg[ch][2]; w0.w = hreg[ch][3];
            w1.x = hreg[ch][4]; w1.y = hreg[ch][5]; w1.z = hreg[ch][6]; w1.w = hreg[ch][7];
            *(uint4*)&lds[ch][r2][8*q]     = w0;
            *(uint4*)&lds[ch][r2][8*q + 4] = w1;
        }
    }
    __syncthreads();

    // ---- stage 3: vertical 7-tap + center recompute + dot + store ----
    if (tid < 128) {
        const int cg = tid & 7, s = tid >> 3;
        const int jb = 8 * cg;                  // out col base (8 cols)
        float D0[8], D1[8], q0[8], q1[8];
#pragma unroll
        for (int e = 0; e < 8; ++e) { D0[e]=0.f; D1[e]=0.f; q0[e]=0.f; q1[e]=0.f; }

        const float* cbase = xb + (size_t)(y0 + 2*s) * W + (x0 + jb);
        f32x4 r0v, r1v, r0w, r1w;               // output accumulators built later
#pragma unroll
        for (int ch = 0; ch < 3; ++ch) {
            f32x2 acc[4];
            acc[0] = f32x2{0.f,0.f}; acc[1] = acc[0]; acc[2] = acc[0]; acc[3] = acc[0];
            uint4 K = {0,0,0,0};
#pragma unroll
            for (int dd = 0; dd < 7; ++dd) {
                const uint4 U = *(const uint4*)&lds[ch][2*s + dd][4*cg];
                if (dd == 0) K = U;
                acc[0] += up2(U.x); acc[1] += up2(U.y);
                acc[2] += up2(U.z); acc[3] += up2(U.w);
            }
            const uint4 U7 = *(const uint4*)&lds[ch][2*s + 7][4*cg];
            f32x2 vrow1[4];
            vrow1[0] = acc[0] + up2(U7.x) - up2(K.x);
            vrow1[1] = acc[1] + up2(U7.y) - up2(K.y);
            vrow1[2] = acc[2] + up2(U7.z) - up2(K.z);
            vrow1[3] = acc[3] + up2(U7.w) - up2(K.w);

            // center x for this channel, both rows (L2-hot re-read)
            const float* cb = cbase + (size_t)ch * HW;
            const f32x4 X0a = *(const f32x4*)(cb);
            const f32x4 X0b = *(const f32x4*)(cb + 4);
            const f32x4 X1a = *(const f32x4*)(cb + W);
            const f32x4 X1b = *(const f32x4*)(cb + W + 4);
#pragma unroll
            for (int e = 0; e < 8; ++e) {
                const float xv0 = (e < 4) ? X0a[e & 3] : X0b[e & 3];
                const float xv1 = (e < 4) ? X1a[e & 3] : X1b[e & 3];
                const float G0v = acc[e >> 1][e & 1];
                const float G1v = vrow1[e >> 1][e & 1];
                D0[e] += xv0 * G0v;  q0[e] += xv0 * xv0;
                D1[e] += xv1 * G1v;  q1[e] += xv1 * xv1;
            }
        }
#pragma unroll
        for (int e = 0; e < 8; ++e) {
            const float inv0 = __builtin_amdgcn_rsqf(fmaxf(q0[e], EPS2));
            const float inv1 = __builtin_amdgcn_rsqf(fmaxf(q1[e], EPS2));
            const float S0 = inv0 * (D0[e] - q0[e] * inv0);
            const float S1 = inv1 * (D1[e] - q1[e] * inv1);
            const float o0 = (48.0f - S0) * 0.125f;
            const float o1 = (48.0f - S1) * 0.125f;
            if (e < 4) { r0v[e & 3] = o0; r1v[e & 3] = o1; }
            else       { r0w[e & 3] = o0; r1w[e & 3] = o1; }
        }
        float* op = out + (size_t)b * HW + (size_t)(y0 + 2*s) * W + (x0 + jb);
        *(f32x4*)(op)         = r0v;
        *(f32x4*)(op + 4)     = r0w;
        *(f32x4*)(op + W)     = r1v;
        *(f32x4*)(op + W + 4) = r1w;
    }
}

extern "C" void kernel_launch(void* const* d_in, const int* in_sizes, int n_in,
                              void* d_out, int out_size, void* d_ws, size_t ws_size,
                              hipStream_t stream) {
    (void)n_in; (void)d_ws; (void)ws_size; (void)out_size;
    const float* x = (const float*)d_in[0];
    float* out = (float*)d_out;

    const int H = 512, W = 512, C = 3;
    const int B = in_sizes[0] / (C * H * W);            // 32

    const int tilesPerImg = (W / TW) * (H / TH);        // 128
    mcnd_kernel<<<B * tilesPerImg, 256, 0, stream>>>(x, out, B, H, W);
}

// Round 4
// 41.409 us; speedup vs baseline: 1.6179x; 1.6179x over previous
//
#include <hip/hip_runtime.h>

// out(p) = (48 - (g·G - g·g)) / 8,  g = x / max(||x||_C, 1e-8),
// G = 7x7 zero-padded box-sum of g (separable H then V).
// LDS: g (packed bf16, stride 44 u32) + h (packed bf16, stride 36 u32).
// No global re-reads; all stores wave-contiguous; strides spread bank-quads.

typedef float f32x2 __attribute__((ext_vector_type(2)));
typedef float f32x4 __attribute__((ext_vector_type(4)));
typedef unsigned int u32;

#define EPS2 1e-16f   // 1/max(sqrt(n2),1e-8) == rsq(max(n2,1e-16))

constexpr int TW  = 64;   // out tile width
constexpr int TH  = 32;   // out tile height
constexpr int RIN = 38;   // staged rows (TH + 6)
constexpr int GS  = 44;   // g row stride (u32); bf16 cols 0..71 used; 11r walks quads
constexpr int HS  = 36;   // h row stride (u32); bf16 cols 0..63 used; 9r walks quads

__device__ __forceinline__ u32 packbf2(float a, float b) {
    // round-half-up bf16 pack (a=lo half, b=hi half); values bounded, no inf/nan
    const u32 ua = __float_as_uint(a), ub = __float_as_uint(b);
    return ((ua + 0x8000u) >> 16) | ((ub + 0x8000u) & 0xffff0000u);
}
__device__ __forceinline__ f32x2 up2(u32 u) {
    f32x2 r;
    r.x = __uint_as_float(u << 16);
    r.y = __uint_as_float(u & 0xffff0000u);
    return r;
}

__global__ __launch_bounds__(256, 4) void mcnd_kernel(const float* __restrict__ x,
                                                      float* __restrict__ out,
                                                      int B, int H, int W) {
    __shared__ __align__(16) u32 gsh[3][RIN][GS];  // 20,064 B
    __shared__ __align__(16) u32 hsh[3][RIN][HS];  // 16,416 B

    const int HW = H * W;
    const int tilesX = W / TW;                  // 8
    const int tilesPerImg = tilesX * (H / TH);  // 128

    // bijective XCD swizzle (gridDim.x % 8 == 0): each XCD gets a contiguous
    // run of tiles -> vertical halo rows re-hit the same XCD's L2.
    const int cpx = gridDim.x >> 3;
    const int wg  = (blockIdx.x & 7) * cpx + (blockIdx.x >> 3);

    const int b  = wg / tilesPerImg;
    const int t  = wg % tilesPerImg;
    const int ty = t / tilesX;
    const int tx = t - ty * tilesX;
    const int y0 = ty * TH;
    const int x0 = tx * TW;

    const float* __restrict__ xb = x + (size_t)b * 3 * HW;
    const int tid = threadIdx.x;

    // ---- phase A: load + normalize -> packed-bf16 g ----
    for (int p = tid; p < RIN * 9; p += 256) {
        const int r = p / 9;
        const int k = p - 9 * r;
        const int gy = y0 + r - 3;
        const int gx = x0 + 8 * k - 4;          // 16B-aligned f32 col base
        f32x4 a0 = {0.f,0.f,0.f,0.f}, a1 = a0, b0 = a0, b1 = a0, c0 = a0, c1 = a0;
        if (gy >= 0 && gy < H) {
            const float* base = xb + (size_t)gy * W + gx;
            if (gx >= 0) {                      // left 4-col chunk
                a0 = *(const f32x4*)(base);
                b0 = *(const f32x4*)(base + HW);
                c0 = *(const f32x4*)(base + 2 * HW);
            }
            if (gx + 8 <= W) {                  // right 4-col chunk
                a1 = *(const f32x4*)(base + 4);
                b1 = *(const f32x4*)(base + HW + 4);
                c1 = *(const f32x4*)(base + 2 * HW + 4);
            }
        }
        float ga[8], gb[8], gc[8];
#pragma unroll
        for (int e = 0; e < 4; ++e) {
            {
                const float n2  = a0[e]*a0[e] + b0[e]*b0[e] + c0[e]*c0[e];
                const float inv = __builtin_amdgcn_rsqf(fmaxf(n2, EPS2));
                ga[e] = a0[e]*inv; gb[e] = b0[e]*inv; gc[e] = c0[e]*inv;
            }
            {
                const float n2  = a1[e]*a1[e] + b1[e]*b1[e] + c1[e]*c1[e];
                const float inv = __builtin_amdgcn_rsqf(fmaxf(n2, EPS2));
                ga[e+4] = a1[e]*inv; gb[e+4] = b1[e]*inv; gc[e+4] = c1[e]*inv;
            }
        }
        uint4 wa, wb, wc;
        wa.x = packbf2(ga[0],ga[1]); wa.y = packbf2(ga[2],ga[3]);
        wa.z = packbf2(ga[4],ga[5]); wa.w = packbf2(ga[6],ga[7]);
        wb.x = packbf2(gb[0],gb[1]); wb.y = packbf2(gb[2],gb[3]);
        wb.z = packbf2(gb[4],gb[5]); wb.w = packbf2(gb[6],gb[7]);
        wc.x = packbf2(gc[0],gc[1]); wc.y = packbf2(gc[2],gc[3]);
        wc.z = packbf2(gc[4],gc[5]); wc.w = packbf2(gc[6],gc[7]);
        *(uint4*)&gsh[0][r][4*k] = wa;
        *(uint4*)&gsh[1][r][4*k] = wb;
        *(uint4*)&gsh[2][r][4*k] = wc;
    }
    __syncthreads();

    // ---- phase B: horizontal 7-tap; wave q owns 16 out cols, lane = row ----
    {
        const int q = tid >> 6;                 // 0..3 (one wave per col group)
        const int r = tid & 63;                 // row
        if (r < RIN) {
#pragma unroll
            for (int ch = 0; ch < 3; ++ch) {
                const u32* row = &gsh[ch][r][0];
                u32 uu[12];
                *(uint4*)&uu[0] = *(const uint4*)(row + 8*q);
                *(uint4*)&uu[4] = *(const uint4*)(row + 8*q + 4);
                *(uint4*)&uu[8] = *(const uint4*)(row + 8*q + 8);
                float c[24];
#pragma unroll
                for (int m = 0; m < 12; ++m) {
                    const f32x2 d = up2(uu[m]);
                    c[2*m] = d.x; c[2*m+1] = d.y;
                }
                // out col 16q+m: window g cols 16q+m+1 .. 16q+m+7 (local 1+m..7+m)
                float hp[16];
                hp[0] = c[1]+c[2]+c[3]+c[4]+c[5]+c[6]+c[7];
#pragma unroll
                for (int m = 1; m < 16; ++m) hp[m] = hp[m-1] - c[m] + c[m+7];
                u32 o[8];
#pragma unroll
                for (int m = 0; m < 8; ++m) o[m] = packbf2(hp[2*m], hp[2*m+1]);
                uint4 w0, w1;
                w0.x = o[0]; w0.y = o[1]; w0.z = o[2]; w0.w = o[3];
                w1.x = o[4]; w1.y = o[5]; w1.z = o[6]; w1.w = o[7];
                *(uint4*)&hsh[ch][r][8*q]     = w0;
                *(uint4*)&hsh[ch][r][8*q + 4] = w1;
            }
        }
    }
    __syncthreads();

    // ---- phase C: vertical 7-tap + dot; thread = 4 cols x rows {rw, rw+16} ----
    {
        const int u  = tid & 15;                // 4-col group
        const int rw = tid >> 4;                // 0..15
        float* op = out + (size_t)b * HW + ((size_t)y0) * W + x0 + 4*u;
#pragma unroll
        for (int half = 0; half < 2; ++half) {
            const int ry = rw + 16 * half;
            f32x2 D01 = {0.f,0.f}, D23 = D01, Q01 = D01, Q23 = D01;
#pragma unroll
            for (int ch = 0; ch < 3; ++ch) {
                f32x2 s0 = {0.f,0.f}, s1 = s0;
#pragma unroll
                for (int dd = 0; dd < 7; ++dd) {
                    const uint2 hv = *(const uint2*)&hsh[ch][ry + dd][2*u];
                    s0 += up2(hv.x);
                    s1 += up2(hv.y);
                }
                const uint2 gv = *(const uint2*)&gsh[ch][ry + 3][2*u + 2];
                const f32x2 g0 = up2(gv.x), g1 = up2(gv.y);
                D01 += g0 * s0;  Q01 += g0 * g0;
                D23 += g1 * s1;  Q23 += g1 * g1;
            }
            f32x4 res;
            res[0] = (48.0f - (D01.x - Q01.x)) * 0.125f;
            res[1] = (48.0f - (D01.y - Q01.y)) * 0.125f;
            res[2] = (48.0f - (D23.x - Q23.x)) * 0.125f;
            res[3] = (48.0f - (D23.y - Q23.y)) * 0.125f;
            *(f32x4*)(op + (size_t)ry * W) = res;   // lanes 0..15 contiguous 256B
        }
    }
}

extern "C" void kernel_launch(void* const* d_in, const int* in_sizes, int n_in,
                              void* d_out, int out_size, void* d_ws, size_t ws_size,
                              hipStream_t stream) {
    (void)n_in; (void)d_ws; (void)ws_size; (void)out_size;
    const float* x = (const float*)d_in[0];
    float* out = (float*)d_out;

    const int H = 512, W = 512, C = 3;
    const int B = in_sizes[0] / (C * H * W);        // 32

    const int tilesPerImg = (W / TW) * (H / TH);    // 128
    mcnd_kernel<<<B * tilesPerImg, 256, 0, stream>>>(x, out, B, H, W);
}